// Round 4
// baseline (373.949 us; speedup 1.0000x reference)
//
#include <hip/hip_runtime.h>
#include <hip/hip_bf16.h>

#define B_ 4
#define S_ 4096
#define DM 512
#define DH 64

#define NEG_BIG (-3.0e38f)
#define MCLAMP  (-1.0e30f)

typedef __attribute__((ext_vector_type(8))) short short8b;   // 8 bf16 (4 VGPRs)
typedef __attribute__((ext_vector_type(4))) float f32x4;     // MFMA C/D

__device__ __forceinline__ f32x4 MFMA16(short8b a, short8b b, f32x4 c) {
    return __builtin_amdgcn_mfma_f32_16x16x32_bf16(a, b, c, 0, 0, 0);
}

__device__ __forceinline__ float bf2f(unsigned short u) {
    unsigned int x = ((unsigned int)u) << 16;
    float f;
    __builtin_memcpy(&f, &x, 4);
    return f;
}
__device__ __forceinline__ unsigned short f2bf_rne(float f) {
    unsigned int u = __float_as_uint(f);
    u += 0x7FFFu + ((u >> 16) & 1u);
    return (unsigned short)(u >> 16);
}

// ---------------------------------------------------------------------------
// Dtype detector (unchanged): flag=1 -> inputs are fp32, 0 -> bf16.
// ---------------------------------------------------------------------------
__global__ void detect_kernel(const unsigned short* __restrict__ u,
                              int* __restrict__ flag) {
    __shared__ int cnt;
    if (threadIdx.x == 0) cnt = 0;
    __syncthreads();
    int w = 0;
    #pragma unroll
    for (int k = 0; k < 8; ++k) {
        unsigned short x = u[threadIdx.x * 8 + k];
        int e = (x >> 7) & 0xFF;
        if (e >= 135 || (e > 0 && e <= 95)) ++w;
    }
    atomicAdd(&cnt, w);
    __syncthreads();
    if (threadIdx.x == 0) *flag = (cnt > 64) ? 1 : 0;
}

// ---------------------------------------------------------------------------
// Projection: tiled fp32 GEMM, hi/lo bf16 split epilogue (unchanged round 3).
// ---------------------------------------------------------------------------
#define TM 64
#define KC 64
#define LDX 68
#define LDW 65

__global__ __launch_bounds__(256) void proj_kernel(
    const void* __restrict__ xq, const void* __restrict__ xk,
    const void* __restrict__ xv,
    const void* __restrict__ Wq, const void* __restrict__ Wk,
    const void* __restrict__ Wv,
    const void* __restrict__ bq, const void* __restrict__ bk,
    const void* __restrict__ bv,
    unsigned short* __restrict__ Qhp, unsigned short* __restrict__ Qlp,
    unsigned short* __restrict__ Khp, unsigned short* __restrict__ Klp,
    unsigned short* __restrict__ Vthp, unsigned short* __restrict__ Vtlp,
    const int* __restrict__ flag)
{
    const int which = blockIdx.y;
    const void* x    = (which == 0) ? xq : (which == 1) ? xk : xv;
    const void* W    = (which == 0) ? Wq : (which == 1) ? Wk : Wv;
    const void* bias = (which == 0) ? bq : (which == 1) ? bk : bv;

    const bool f32 = (*flag != 0);
    const int row0 = blockIdx.x * TM;
    const int t    = threadIdx.x;
    const int tr   = t >> 4;
    const int tc   = t & 15;

    __shared__ float Xs[TM][LDX];
    __shared__ float Ws[KC][LDW];

    float acc[4][4];
    #pragma unroll
    for (int r = 0; r < 4; ++r)
        #pragma unroll
        for (int h = 0; h < 4; ++h) acc[r][h] = 0.f;

    for (int kc = 0; kc < DM; kc += KC) {
        __syncthreads();
        if (f32) {
            const float* xb = (const float*)x;
            #pragma unroll
            for (int jv = 0; jv < 4; ++jv) {
                int lidx = jv * 256 + t;
                int r = lidx >> 4, kq = lidx & 15;
                float4 v = *reinterpret_cast<const float4*>(
                    xb + (size_t)(row0 + r) * DM + kc + kq * 4);
                *reinterpret_cast<float4*>(&Xs[r][kq * 4]) = v;
            }
            const float* wb = (const float*)W;
            #pragma unroll
            for (int jv = 0; jv < 4; ++jv) {
                int lidx = jv * 256 + t;
                int h = lidx >> 4, kq = lidx & 15;
                float4 v = *reinterpret_cast<const float4*>(
                    wb + (size_t)h * DM + kc + kq * 4);
                Ws[kq * 4 + 0][h] = v.x;
                Ws[kq * 4 + 1][h] = v.y;
                Ws[kq * 4 + 2][h] = v.z;
                Ws[kq * 4 + 3][h] = v.w;
            }
        } else {
            const unsigned short* xb = (const unsigned short*)x;
            #pragma unroll
            for (int jv = 0; jv < 4; ++jv) {
                int lidx = jv * 256 + t;
                int r = lidx >> 4, kq = lidx & 15;
                ushort4 u = *reinterpret_cast<const ushort4*>(
                    xb + (size_t)(row0 + r) * DM + kc + kq * 4);
                Xs[r][kq * 4 + 0] = bf2f(u.x);
                Xs[r][kq * 4 + 1] = bf2f(u.y);
                Xs[r][kq * 4 + 2] = bf2f(u.z);
                Xs[r][kq * 4 + 3] = bf2f(u.w);
            }
            const unsigned short* wb = (const unsigned short*)W;
            #pragma unroll
            for (int jv = 0; jv < 4; ++jv) {
                int lidx = jv * 256 + t;
                int h = lidx >> 4, kq = lidx & 15;
                ushort4 u = *reinterpret_cast<const ushort4*>(
                    wb + (size_t)h * DM + kc + kq * 4);
                Ws[kq * 4 + 0][h] = bf2f(u.x);
                Ws[kq * 4 + 1][h] = bf2f(u.y);
                Ws[kq * 4 + 2][h] = bf2f(u.z);
                Ws[kq * 4 + 3][h] = bf2f(u.w);
            }
        }
        __syncthreads();

        #pragma unroll
        for (int k4 = 0; k4 < KC / 4; ++k4) {
            float4 xv4[4], wv4[4];
            #pragma unroll
            for (int r = 0; r < 4; ++r)
                xv4[r] = *reinterpret_cast<const float4*>(&Xs[tr * 4 + r][k4 * 4]);
            #pragma unroll
            for (int j = 0; j < 4; ++j)
                wv4[j] = *reinterpret_cast<const float4*>(&Ws[k4 * 4 + j][tc * 4]);
            #pragma unroll
            for (int r = 0; r < 4; ++r) {
                const float* xp = reinterpret_cast<const float*>(&xv4[r]);
                #pragma unroll
                for (int j = 0; j < 4; ++j) {
                    const float* wp = reinterpret_cast<const float*>(&wv4[j]);
                    float xs = xp[j];
                    #pragma unroll
                    for (int h = 0; h < 4; ++h)
                        acc[r][h] = fmaf(xs, wp[h], acc[r][h]);
                }
            }
        }
    }

    float bs[4];
    #pragma unroll
    for (int h = 0; h < 4; ++h)
        bs[h] = f32 ? ((const float*)bias)[tc * 4 + h]
                    : bf2f(((const unsigned short*)bias)[tc * 4 + h]);

    if (which < 2) {
        unsigned short* ph = (which == 0) ? Qhp : Khp;
        unsigned short* pl = (which == 0) ? Qlp : Klp;
        const float scale = (which == 0) ? 0.125f : 1.0f;   // 1/sqrt(64) in Q
        #pragma unroll
        for (int r = 0; r < 4; ++r) {
            ushort4 h4, l4v;
            unsigned short* hp = (unsigned short*)&h4;
            unsigned short* lp = (unsigned short*)&l4v;
            #pragma unroll
            for (int h = 0; h < 4; ++h) {
                float v = (acc[r][h] + bs[h]) * scale;
                unsigned short hb = f2bf_rne(v);
                hp[h] = hb;
                lp[h] = f2bf_rne(v - bf2f(hb));
            }
            const size_t off = (size_t)(row0 + tr * 4 + r) * DH + tc * 4;
            *reinterpret_cast<ushort4*>(ph + off) = h4;
            *reinterpret_cast<ushort4*>(pl + off) = l4v;
        }
    } else {
        const int bb = row0 >> 12;          // batch (4096 % 64 == 0)
        const int s0 = row0 & 4095;
        #pragma unroll
        for (int j = 0; j < 4; ++j) {
            ushort4 h4, l4v;
            unsigned short* hp = (unsigned short*)&h4;
            unsigned short* lp = (unsigned short*)&l4v;
            #pragma unroll
            for (int r = 0; r < 4; ++r) {
                float v = acc[r][j] + bs[j];
                unsigned short hb = f2bf_rne(v);
                hp[r] = hb;
                lp[r] = f2bf_rne(v - bf2f(hb));
            }
            const size_t off = (size_t)(bb * 64 + tc * 4 + j) * S_ + s0 + tr * 4;
            *reinterpret_cast<ushort4*>(Vthp + off) = h4;
            *reinterpret_cast<ushort4*>(Vtlp + off) = l4v;
        }
    }
}

// ---------------------------------------------------------------------------
// Flash attention v4: 8 waves (512 thr), 32q x 128k tiles, 2 barriers/tile.
//  - Balanced pairing (qt, 127-qt): every block does exactly 33 k-tiles.
//  - Wave w = (qh = w&1 -> 16 q-rows, kh = w>>1 -> 32-key group).
//  - Each kh group runs an INDEPENDENT online softmax (m,l,O-partial) over
//    its own key columns; merged once at epilogue via log-sum-exp. This
//    removes the per-tile cross-wave combine barriers.
//  - Empty-group hazard: a fully-masked group would hit exp(NEG_BIG-NEG_BIG)
//    = 1; fixed by clamping m_new >= -1e30 so masked scores stay exp(-3e38)=0.
//  - P is wave-private (write + read own 16x32 block): lgkmcnt fence only.
//  - QK = 3-pass hi/lo bf16 MFMA (fp32-grade); PV = P x (V_hi + V_lo).
//  - All LDS tiles XOR-swizzled (byte ^= (row&7)<<4), write+read consistent.
//  - Q region (8K) is aliased by P after the kt==0 fragment load (one extra
//    barrier at kt==0 orders the alias).
// LDS: 73728 B smem + 1152 B stats = 74.9 KB. VGPR ~130 -> 2 waves/SIMD.
// ---------------------------------------------------------------------------
__global__ __launch_bounds__(512, 1) void flash_kernel(
    const unsigned short* __restrict__ Qh, const unsigned short* __restrict__ Ql,
    const unsigned short* __restrict__ Kh, const unsigned short* __restrict__ Kl,
    const unsigned short* __restrict__ Vth, const unsigned short* __restrict__ Vtl,
    void* __restrict__ out, const int* __restrict__ flag)
{
    const int pair = blockIdx.x;   // 0..63
    const int b    = blockIdx.y;   // 0..3
    const int t    = threadIdx.x;
    const int lane = t & 63;
    const int w    = t >> 6;       // 0..7
    const int qh   = w & 1;        // q half (16 rows)
    const int kh   = w >> 1;       // key group (32 cols)
    const int l15  = lane & 15;
    const int l4   = lane >> 4;

    // smem layout (bytes):
    //   [0,     8192)  Q planes (2 x 32x64 bf16)  -- aliased by P (32x128 bf16)
    //   [8192, 40960)  K planes (2 x 128x64 bf16) -- aliased by Opart (4x32x64 f32)
    //   [40960,73728)  V planes (2 x 64x128 bf16, transposed [d][s])
    __shared__ __align__(16) char smem[73728];
    __shared__ float Mg[4][32];
    __shared__ float Lg[4][32];
    __shared__ float Ltot[32];

    const size_t bS = (size_t)b * S_;
    const bool f32o = (*flag != 0);

    // staging maps
    const int qp   = t >> 8;            // Q plane
    const int qrow = (t & 255) >> 3;    // 0..31
    const int qsg  = t & 7;             // 8 x 16B per 128B row
    const int krow = t >> 2;            // 0..127 (K rows, 128B each)
    const int ksg  = t & 3;             // 4 x 32B
    const int vrow = t >> 3;            // 0..63  (V d-rows, 256B each)
    const int vsg  = t & 7;             // 8 x 32B

    #pragma unroll 1
    for (int hf = 0; hf < 2; ++hf) {
        const int qt = hf ? (127 - pair) : pair;
        const int q0 = qt << 5;
        const int nk = (qt >> 2) + 1;   // 128-key tiles; pair sum is always 33

        __syncthreads();   // prior half's epilogue reads complete
        // stage Q (pre-scaled hi/lo planes)
        {
            const unsigned short* src = qp ? Ql : Qh;
            uint4 v = *reinterpret_cast<const uint4*>(
                src + (bS + q0 + qrow) * 64 + qsg * 8);
            const int off = qp * 4096 + qrow * 128 +
                            ((qsg * 16) ^ ((qrow & 7) << 4));
            *reinterpret_cast<uint4*>(smem + off) = v;
        }

        uint4 rk[2][2], rv[2][2];
        auto load_tile = [&](int kt) {
            #pragma unroll
            for (int u = 0; u < 2; ++u) {
                const size_t ko = (bS + (size_t)kt * 128 + krow) * 64 + ksg * 16 + u * 8;
                rk[0][u] = *reinterpret_cast<const uint4*>(Kh + ko);
                rk[1][u] = *reinterpret_cast<const uint4*>(Kl + ko);
                const size_t vo = (size_t)(b * 64 + vrow) * S_ + (size_t)kt * 128 + vsg * 16 + u * 8;
                rv[0][u] = *reinterpret_cast<const uint4*>(Vth + vo);
                rv[1][u] = *reinterpret_cast<const uint4*>(Vtl + vo);
            }
        };
        load_tile(0);

        short8b qf[2][2];   // [plane][ks]
        f32x4 of[4];        // O partial: rows (qh,l4,r) x d = ct*16+l15
        of[0] = f32x4{0.f, 0.f, 0.f, 0.f};
        of[1] = f32x4{0.f, 0.f, 0.f, 0.f};
        of[2] = f32x4{0.f, 0.f, 0.f, 0.f};
        of[3] = f32x4{0.f, 0.f, 0.f, 0.f};
        float mrun[4], lrun[4];
        #pragma unroll
        for (int r = 0; r < 4; ++r) { mrun[r] = NEG_BIG; lrun[r] = 0.f; }

        #pragma unroll 1
        for (int kt = 0; kt < nk; ++kt) {
            __syncthreads();   // prev tile's K/V reads done
            #pragma unroll
            for (int p = 0; p < 2; ++p) {
                #pragma unroll
                for (int u = 0; u < 2; ++u) {
                    const int koff = 8192 + p * 16384 + krow * 128 +
                                     ((ksg * 32 + u * 16) ^ ((krow & 7) << 4));
                    *reinterpret_cast<uint4*>(smem + koff) = rk[p][u];
                    const int voff = 40960 + p * 16384 + vrow * 256 +
                                     ((vsg * 32 + u * 16) ^ ((vrow & 7) << 4));
                    *reinterpret_cast<uint4*>(smem + voff) = rv[p][u];
                }
            }
            if (kt + 1 < nk) load_tile(kt + 1);   // hide global latency
            __syncthreads();   // stage visible

            if (kt == 0) {
                #pragma unroll
                for (int p = 0; p < 2; ++p)
                    #pragma unroll
                    for (int ks = 0; ks < 2; ++ks) {
                        const int row = qh * 16 + l15;
                        const int off = p * 4096 + row * 128 +
                                        ((ks * 64 + l4 * 16) ^ ((row & 7) << 4));
                        qf[p][ks] = *reinterpret_cast<const short8b*>(smem + off);
                    }
                __syncthreads();   // all Q reads done before P aliases region
            }

            // ---- QK: 3-pass split-precision MFMA over this wave's 32 cols ----
            f32x4 sc[2];
            #pragma unroll
            for (int ct = 0; ct < 2; ++ct) {
                f32x4 a = f32x4{0.f, 0.f, 0.f, 0.f};
                #pragma unroll
                for (int ks = 0; ks < 2; ++ks) {
                    const int row = kh * 32 + ct * 16 + l15;
                    const int off = 8192 + row * 128 +
                                    ((ks * 64 + l4 * 16) ^ ((row & 7) << 4));
                    short8b bh = *reinterpret_cast<const short8b*>(smem + off);
                    short8b bl = *reinterpret_cast<const short8b*>(smem + off + 16384);
                    a = MFMA16(qf[1][ks], bh, a);   // qlo * khi
                    a = MFMA16(qf[0][ks], bl, a);   // qhi * klo
                    a = MFMA16(qf[0][ks], bh, a);   // qhi * khi
                }
                sc[ct] = a;
            }

            // causal mask: only the final k-tile
            if (kt == nk - 1) {
                #pragma unroll
                for (int ct = 0; ct < 2; ++ct) {
                    const int col = kt * 128 + kh * 32 + ct * 16 + l15;
                    #pragma unroll
                    for (int r = 0; r < 4; ++r) {
                        const int row = q0 + qh * 16 + l4 * 4 + r;
                        if (col > row) sc[ct][r] = NEG_BIG;
                    }
                }
            }

            // ---- wave-local online softmax (per kh group) ----
            float pm[4];
            #pragma unroll
            for (int r = 0; r < 4; ++r) pm[r] = fmaxf(sc[0][r], sc[1][r]);
            #pragma unroll
            for (int s = 1; s < 16; s <<= 1)
                #pragma unroll
                for (int r = 0; r < 4; ++r)
                    pm[r] = fmaxf(pm[r], __shfl_xor(pm[r], s));

            float alpha[4], ps[4];
            #pragma unroll
            for (int r = 0; r < 4; ++r) {
                const float mn = fmaxf(fmaxf(mrun[r], pm[r]), MCLAMP);
                alpha[r] = __expf(mrun[r] - mn);      // first tile: 0
                mrun[r] = mn;
                sc[0][r] = __expf(sc[0][r] - mn);     // masked -> 0 (mn>=-1e30)
                sc[1][r] = __expf(sc[1][r] - mn);
                ps[r] = sc[0][r] + sc[1][r];
            }
            #pragma unroll
            for (int s = 1; s < 16; s <<= 1)
                #pragma unroll
                for (int r = 0; r < 4; ++r) ps[r] += __shfl_xor(ps[r], s);
            #pragma unroll
            for (int r = 0; r < 4; ++r) lrun[r] = lrun[r] * alpha[r] + ps[r];
            #pragma unroll
            for (int c = 0; c < 4; ++c)
                #pragma unroll
                for (int r = 0; r < 4; ++r) of[c][r] *= alpha[r];

            // ---- P write (bf16, wave-private region, swizzled) ----
            #pragma unroll
            for (int ct = 0; ct < 2; ++ct)
                #pragma unroll
                for (int r = 0; r < 4; ++r) {
                    const int row = qh * 16 + l4 * 4 + r;
                    const int col = kh * 32 + ct * 16 + l15;
                    const int off = row * 256 + ((col * 2) ^ ((row & 7) << 4));
                    *reinterpret_cast<unsigned short*>(smem + off) =
                        f2bf_rne(sc[ct][r]);
                }
            asm volatile("s_waitcnt lgkmcnt(0)" ::: "memory");
            __builtin_amdgcn_sched_barrier(0);

            // ---- P read (own block) + PV ----
            short8b pf;
            {
                const int row = qh * 16 + l15;
                const int off = row * 256 + ((kh * 64 + l4 * 16) ^ ((row & 7) << 4));
                pf = *reinterpret_cast<const short8b*>(smem + off);
            }
            #pragma unroll
            for (int ct = 0; ct < 4; ++ct) {
                const int vr = ct * 16 + l15;   // d-row of Vt
                const int voff = 40960 + vr * 256 +
                                 ((kh * 64 + l4 * 16) ^ ((vr & 7) << 4));
                short8b vh = *reinterpret_cast<const short8b*>(smem + voff);
                short8b vl = *reinterpret_cast<const short8b*>(smem + voff + 16384);
                of[ct] = MFMA16(pf, vl, of[ct]);
                of[ct] = MFMA16(pf, vh, of[ct]);
            }
        }

        // ---- epilogue: merge the 4 independent kh groups ----
        if (l15 == 0) {
            #pragma unroll
            for (int r = 0; r < 4; ++r) {
                const int row = qh * 16 + l4 * 4 + r;
                Mg[kh][row] = mrun[r];
                Lg[kh][row] = lrun[r];
            }
        }
        __syncthreads();   // stats visible; all K reads long done (Opart alias)

        float* Op = reinterpret_cast<float*>(smem + 8192);   // alias K region
        #pragma unroll
        for (int r = 0; r < 4; ++r) {
            const int row = qh * 16 + l4 * 4 + r;
            const float M = fmaxf(fmaxf(Mg[0][row], Mg[1][row]),
                                  fmaxf(Mg[2][row], Mg[3][row]));
            const float L = Lg[0][row] * __expf(Mg[0][row] - M)
                          + Lg[1][row] * __expf(Mg[1][row] - M)
                          + Lg[2][row] * __expf(Mg[2][row] - M)
                          + Lg[3][row] * __expf(Mg[3][row] - M);
            const float al = __expf(mrun[r] - M);   // empty group: -> 0
            #pragma unroll
            for (int c = 0; c < 4; ++c)
                Op[kh * 2048 + row * 64 + c * 16 + l15] = of[c][r] * al;
            if (kh == 0 && l15 == 0) Ltot[row] = L;
        }
        __syncthreads();

        // final reduce across groups + store
        {
            const int row = t >> 4;
            const int d0  = (t & 15) << 2;
            float4 s = {0.f, 0.f, 0.f, 0.f};
            #pragma unroll
            for (int g = 0; g < 4; ++g) {
                float4 v = *reinterpret_cast<const float4*>(
                    Op + g * 2048 + row * 64 + d0);
                s.x += v.x; s.y += v.y; s.z += v.z; s.w += v.w;
            }
            const float inv = 1.0f / Ltot[row];
            const size_t oi = (bS + q0 + row) * 64 + d0;
            if (f32o) {
                float4 o;
                o.x = s.x * inv; o.y = s.y * inv;
                o.z = s.z * inv; o.w = s.w * inv;
                *reinterpret_cast<float4*>((float*)out + oi) = o;
            } else {
                ushort4 o;
                o.x = f2bf_rne(s.x * inv);
                o.y = f2bf_rne(s.y * inv);
                o.z = f2bf_rne(s.z * inv);
                o.w = f2bf_rne(s.w * inv);
                *reinterpret_cast<ushort4*>((unsigned short*)out + oi) = o;
            }
        }
    }
}

extern "C" void kernel_launch(void* const* d_in, const int* in_sizes, int n_in,
                              void* d_out, int out_size, void* d_ws, size_t ws_size,
                              hipStream_t stream) {
    // workspace: 6 bf16 planes (Qh,Ql,Kh,Kl,Vth,Vtl) = 6 x 2MB = 12MB, + flag
    const size_t NP = (size_t)B_ * S_ * DH;
    unsigned short* Qhp  = (unsigned short*)d_ws;
    unsigned short* Qlp  = Qhp + NP;
    unsigned short* Khp  = Qhp + 2 * NP;
    unsigned short* Klp  = Qhp + 3 * NP;
    unsigned short* Vthp = Qhp + 4 * NP;
    unsigned short* Vtlp = Qhp + 5 * NP;
    int* flag = (int*)(Qhp + 6 * NP);

    detect_kernel<<<1, 256, 0, stream>>>((const unsigned short*)d_in[0], flag);

    proj_kernel<<<dim3(B_ * S_ / TM, 3), 256, 0, stream>>>(
        d_in[0], d_in[1], d_in[2],   // xq, xk, xv
        d_in[3], d_in[5], d_in[7],   // Wq, Wk, Wv
        d_in[4], d_in[6], d_in[8],   // bq, bk, bv
        Qhp, Qlp, Khp, Klp, Vthp, Vtlp, flag);

    flash_kernel<<<dim3(64, B_), 512, 0, stream>>>(
        Qhp, Qlp, Khp, Klp, Vthp, Vtlp, d_out, flag);
}

// Round 5
// 247.115 us; speedup vs baseline: 1.5133x; 1.5133x over previous
//
#include <hip/hip_runtime.h>
#include <hip/hip_bf16.h>

#define B_ 4
#define S_ 4096
#define DM 512
#define DH 64

#define NEG_BIG (-3.0e38f)
#define MCLAMP  (-1.0e30f)

typedef __attribute__((ext_vector_type(8))) short short8b;   // 8 bf16 (4 VGPRs)
typedef __attribute__((ext_vector_type(4))) float f32x4;     // MFMA C/D

__device__ __forceinline__ f32x4 MFMA16(short8b a, short8b b, f32x4 c) {
    return __builtin_amdgcn_mfma_f32_16x16x32_bf16(a, b, c, 0, 0, 0);
}

__device__ __forceinline__ float bf2f(unsigned short u) {
    unsigned int x = ((unsigned int)u) << 16;
    float f;
    __builtin_memcpy(&f, &x, 4);
    return f;
}
__device__ __forceinline__ unsigned short f2bf_rne(float f) {
    unsigned int u = __float_as_uint(f);
    u += 0x7FFFu + ((u >> 16) & 1u);
    return (unsigned short)(u >> 16);
}

// async HBM->LDS DMA, 16B/lane. LDS dest is wave-uniform base + lane*16;
// global src is PER-LANE (carries the swizzle). Completion tracked by vmcnt.
__device__ __forceinline__ void gload16(const void* gp, void* lp) {
    __builtin_amdgcn_global_load_lds(
        (const __attribute__((address_space(1))) void*)gp,
        (__attribute__((address_space(3))) void*)lp, 16, 0, 0);
}

// ---------------------------------------------------------------------------
// Dtype detector (unchanged): flag=1 -> inputs are fp32, 0 -> bf16.
// ---------------------------------------------------------------------------
__global__ void detect_kernel(const unsigned short* __restrict__ u,
                              int* __restrict__ flag) {
    __shared__ int cnt;
    if (threadIdx.x == 0) cnt = 0;
    __syncthreads();
    int w = 0;
    #pragma unroll
    for (int k = 0; k < 8; ++k) {
        unsigned short x = u[threadIdx.x * 8 + k];
        int e = (x >> 7) & 0xFF;
        if (e >= 135 || (e > 0 && e <= 95)) ++w;
    }
    atomicAdd(&cnt, w);
    __syncthreads();
    if (threadIdx.x == 0) *flag = (cnt > 64) ? 1 : 0;
}

// ---------------------------------------------------------------------------
// Projection: tiled fp32 GEMM, hi/lo bf16 split epilogue (unchanged round 3).
// ---------------------------------------------------------------------------
#define TM 64
#define KC 64
#define LDX 68
#define LDW 65

__global__ __launch_bounds__(256) void proj_kernel(
    const void* __restrict__ xq, const void* __restrict__ xk,
    const void* __restrict__ xv,
    const void* __restrict__ Wq, const void* __restrict__ Wk,
    const void* __restrict__ Wv,
    const void* __restrict__ bq, const void* __restrict__ bk,
    const void* __restrict__ bv,
    unsigned short* __restrict__ Qhp, unsigned short* __restrict__ Qlp,
    unsigned short* __restrict__ Khp, unsigned short* __restrict__ Klp,
    unsigned short* __restrict__ Vthp, unsigned short* __restrict__ Vtlp,
    const int* __restrict__ flag)
{
    const int which = blockIdx.y;
    const void* x    = (which == 0) ? xq : (which == 1) ? xk : xv;
    const void* W    = (which == 0) ? Wq : (which == 1) ? Wk : Wv;
    const void* bias = (which == 0) ? bq : (which == 1) ? bk : bv;

    const bool f32 = (*flag != 0);
    const int row0 = blockIdx.x * TM;
    const int t    = threadIdx.x;
    const int tr   = t >> 4;
    const int tc   = t & 15;

    __shared__ float Xs[TM][LDX];
    __shared__ float Ws[KC][LDW];

    float acc[4][4];
    #pragma unroll
    for (int r = 0; r < 4; ++r)
        #pragma unroll
        for (int h = 0; h < 4; ++h) acc[r][h] = 0.f;

    for (int kc = 0; kc < DM; kc += KC) {
        __syncthreads();
        if (f32) {
            const float* xb = (const float*)x;
            #pragma unroll
            for (int jv = 0; jv < 4; ++jv) {
                int lidx = jv * 256 + t;
                int r = lidx >> 4, kq = lidx & 15;
                float4 v = *reinterpret_cast<const float4*>(
                    xb + (size_t)(row0 + r) * DM + kc + kq * 4);
                *reinterpret_cast<float4*>(&Xs[r][kq * 4]) = v;
            }
            const float* wb = (const float*)W;
            #pragma unroll
            for (int jv = 0; jv < 4; ++jv) {
                int lidx = jv * 256 + t;
                int h = lidx >> 4, kq = lidx & 15;
                float4 v = *reinterpret_cast<const float4*>(
                    wb + (size_t)h * DM + kc + kq * 4);
                Ws[kq * 4 + 0][h] = v.x;
                Ws[kq * 4 + 1][h] = v.y;
                Ws[kq * 4 + 2][h] = v.z;
                Ws[kq * 4 + 3][h] = v.w;
            }
        } else {
            const unsigned short* xb = (const unsigned short*)x;
            #pragma unroll
            for (int jv = 0; jv < 4; ++jv) {
                int lidx = jv * 256 + t;
                int r = lidx >> 4, kq = lidx & 15;
                ushort4 u = *reinterpret_cast<const ushort4*>(
                    xb + (size_t)(row0 + r) * DM + kc + kq * 4);
                Xs[r][kq * 4 + 0] = bf2f(u.x);
                Xs[r][kq * 4 + 1] = bf2f(u.y);
                Xs[r][kq * 4 + 2] = bf2f(u.z);
                Xs[r][kq * 4 + 3] = bf2f(u.w);
            }
            const unsigned short* wb = (const unsigned short*)W;
            #pragma unroll
            for (int jv = 0; jv < 4; ++jv) {
                int lidx = jv * 256 + t;
                int h = lidx >> 4, kq = lidx & 15;
                ushort4 u = *reinterpret_cast<const ushort4*>(
                    wb + (size_t)h * DM + kc + kq * 4);
                Ws[kq * 4 + 0][h] = bf2f(u.x);
                Ws[kq * 4 + 1][h] = bf2f(u.y);
                Ws[kq * 4 + 2][h] = bf2f(u.z);
                Ws[kq * 4 + 3][h] = bf2f(u.w);
            }
        }
        __syncthreads();

        #pragma unroll
        for (int k4 = 0; k4 < KC / 4; ++k4) {
            float4 xv4[4], wv4[4];
            #pragma unroll
            for (int r = 0; r < 4; ++r)
                xv4[r] = *reinterpret_cast<const float4*>(&Xs[tr * 4 + r][k4 * 4]);
            #pragma unroll
            for (int j = 0; j < 4; ++j)
                wv4[j] = *reinterpret_cast<const float4*>(&Ws[k4 * 4 + j][tc * 4]);
            #pragma unroll
            for (int r = 0; r < 4; ++r) {
                const float* xp = reinterpret_cast<const float*>(&xv4[r]);
                #pragma unroll
                for (int j = 0; j < 4; ++j) {
                    const float* wp = reinterpret_cast<const float*>(&wv4[j]);
                    float xs = xp[j];
                    #pragma unroll
                    for (int h = 0; h < 4; ++h)
                        acc[r][h] = fmaf(xs, wp[h], acc[r][h]);
                }
            }
        }
    }

    float bs[4];
    #pragma unroll
    for (int h = 0; h < 4; ++h)
        bs[h] = f32 ? ((const float*)bias)[tc * 4 + h]
                    : bf2f(((const unsigned short*)bias)[tc * 4 + h]);

    if (which < 2) {
        unsigned short* ph = (which == 0) ? Qhp : Khp;
        unsigned short* pl = (which == 0) ? Qlp : Klp;
        const float scale = (which == 0) ? 0.125f : 1.0f;   // 1/sqrt(64) in Q
        #pragma unroll
        for (int r = 0; r < 4; ++r) {
            ushort4 h4, l4v;
            unsigned short* hp = (unsigned short*)&h4;
            unsigned short* lp = (unsigned short*)&l4v;
            #pragma unroll
            for (int h = 0; h < 4; ++h) {
                float v = (acc[r][h] + bs[h]) * scale;
                unsigned short hb = f2bf_rne(v);
                hp[h] = hb;
                lp[h] = f2bf_rne(v - bf2f(hb));
            }
            const size_t off = (size_t)(row0 + tr * 4 + r) * DH + tc * 4;
            *reinterpret_cast<ushort4*>(ph + off) = h4;
            *reinterpret_cast<ushort4*>(pl + off) = l4v;
        }
    } else {
        const int bb = row0 >> 12;          // batch (4096 % 64 == 0)
        const int s0 = row0 & 4095;
        #pragma unroll
        for (int j = 0; j < 4; ++j) {
            ushort4 h4, l4v;
            unsigned short* hp = (unsigned short*)&h4;
            unsigned short* lp = (unsigned short*)&l4v;
            #pragma unroll
            for (int r = 0; r < 4; ++r) {
                float v = acc[r][j] + bs[j];
                unsigned short hb = f2bf_rne(v);
                hp[r] = hb;
                lp[r] = f2bf_rne(v - bf2f(hb));
            }
            const size_t off = (size_t)(bb * 64 + tc * 4 + j) * S_ + s0 + tr * 4;
            *reinterpret_cast<ushort4*>(Vthp + off) = h4;
            *reinterpret_cast<ushort4*>(Vtlp + off) = l4v;
        }
    }
}

// ---------------------------------------------------------------------------
// Flash attention v5: v4 structure, but K/V staged via global_load_lds DMA
// into DOUBLE-BUFFERED LDS (no staging registers -> no scratch spill).
//  - Swizzle moved to the GLOBAL source address (per-lane); LDS dest linear;
//    read-side swizzle identical to v4 (write-perm == read-perm involution).
//  - One barrier per tile: prefetch kt+1 issued before compute on kt and
//    drained by the end-of-tile __syncthreads (implicit vmcnt(0)).
//  - 8 waves (512 thr): wave = (qh 16 q-rows, kh 32-key group); independent
//    per-group online softmax, merged at epilogue (log-sum-exp, MCLAMP).
// smem: [0,8192) Q planes / P (alias); [8192,+65536) buf0 {Khi,Klo,Vhi,Vlo};
//       [73728,+65536) buf1. Total 139264 B + 1.1 KB stats.
// ---------------------------------------------------------------------------
__global__ __launch_bounds__(512, 2) void flash_kernel(
    const unsigned short* __restrict__ Qh, const unsigned short* __restrict__ Ql,
    const unsigned short* __restrict__ Kh, const unsigned short* __restrict__ Kl,
    const unsigned short* __restrict__ Vth, const unsigned short* __restrict__ Vtl,
    void* __restrict__ out, const int* __restrict__ flag)
{
    const int pair = blockIdx.x;   // 0..63
    const int b    = blockIdx.y;   // 0..3
    const int t    = threadIdx.x;
    const int lane = t & 63;
    const int w    = t >> 6;       // 0..7
    const int qh   = w & 1;        // q half (16 rows)
    const int kh   = w >> 1;       // key group (32 cols)
    const int l15  = lane & 15;
    const int l4   = lane >> 4;

    __shared__ __align__(16) char smem[8192 + 2 * 65536];
    __shared__ float Mg[4][32];
    __shared__ float Lg[4][32];
    __shared__ float Ltot[32];

    const size_t bS = (size_t)b * S_;
    const bool f32o = (*flag != 0);

    // Q staging map (per-thread stores, 1 uint4 each)
    const int qp   = t >> 8;            // plane
    const int qrow = (t & 255) >> 3;    // 0..31
    const int qsg  = t & 7;

    // K staging lane constants: chunk = 8 rows x 128B. Lane l covers
    // row l>>3, seg l&7; source byte pre-swizzled so linear LDS == swizzled.
    const int klaneoff = ((lane >> 3) << 7) +
                         ((((lane & 7) << 4)) ^ ((lane >> 3) << 4));
    // V staging lane constants: chunk = 4 rows x 256B; row parity par=cvp&1.
    const int vrl = lane >> 4;          // 0..3
    const int voff0 = (vrl << 13) + ((((lane & 15) << 4)) ^ (vrl << 4));
    const int voff1 = (vrl << 13) + ((((lane & 15) << 4)) ^ ((4 + vrl) << 4));

    const char* Khb = (const char*)Kh + bS * 128;          // 128 B per row
    const char* Klb = (const char*)Kl + bS * 128;
    const char* Vhb = (const char*)Vth + (size_t)b * 64 * 8192;  // 8192 B per d-row
    const char* Vlb = (const char*)Vtl + (size_t)b * 64 * 8192;

    auto issue_tile = [&](int kt, int bsel) {
        char* buf = smem + 8192 + bsel * 65536;
        if (w < 4) {
            // K: 32 chunks (2 planes x 16), waves 0..3 x 8 issues
            #pragma unroll
            for (int j = 0; j < 8; ++j) {
                const int c2  = w * 8 + j;          // 0..31
                const int p   = c2 >> 4;
                const int ckp = c2 & 15;
                const char* g = (p ? Klb : Khb) +
                                (size_t)kt * 16384 + ckp * 1024 + klaneoff;
                gload16(g, buf + p * 16384 + ckp * 1024);
            }
        } else {
            // V: 32 chunks (2 planes x 16), waves 4..7 x 8 issues
            #pragma unroll
            for (int j = 0; j < 8; ++j) {
                const int c2  = (w - 4) * 8 + j;    // 0..31
                const int p   = c2 >> 4;
                const int cvp = c2 & 15;
                const int vo  = (cvp & 1) ? voff1 : voff0;
                const char* g = (p ? Vlb : Vhb) +
                                (size_t)cvp * 32768 + (size_t)kt * 256 + vo;
                gload16(g, buf + 32768 + p * 16384 + cvp * 1024);
            }
        }
    };

    #pragma unroll 1
    for (int hf = 0; hf < 2; ++hf) {
        const int qt = hf ? (127 - pair) : pair;
        const int q0 = qt << 5;
        const int nk = (qt >> 2) + 1;   // 128-key tiles; pair sum is 33

        __syncthreads();   // prior half fully done (epilogue reads complete)

        // stage Q (pre-scaled hi/lo planes, swizzled, per-thread)
        {
            const unsigned short* src = qp ? Ql : Qh;
            uint4 v = *reinterpret_cast<const uint4*>(
                src + (bS + q0 + qrow) * 64 + qsg * 8);
            const int off = qp * 4096 + qrow * 128 +
                            ((qsg * 16) ^ ((qrow & 7) << 4));
            *reinterpret_cast<uint4*>(smem + off) = v;
        }
        issue_tile(0, 0);
        __syncthreads();   // Q stores + tile0 DMA complete (vmcnt drained)

        // Q fragments (once per half)
        short8b qf[2][2];   // [plane][ks]
        #pragma unroll
        for (int p = 0; p < 2; ++p)
            #pragma unroll
            for (int ks = 0; ks < 2; ++ks) {
                const int row = qh * 16 + l15;
                const int off = p * 4096 + row * 128 +
                                ((ks * 64 + l4 * 16) ^ ((row & 7) << 4));
                qf[p][ks] = *reinterpret_cast<const short8b*>(smem + off);
            }
        __syncthreads();   // all Q reads done before P aliases the region

        f32x4 of[4];
        of[0] = f32x4{0.f, 0.f, 0.f, 0.f};
        of[1] = f32x4{0.f, 0.f, 0.f, 0.f};
        of[2] = f32x4{0.f, 0.f, 0.f, 0.f};
        of[3] = f32x4{0.f, 0.f, 0.f, 0.f};
        float mrun[4], lrun[4];
        #pragma unroll
        for (int r = 0; r < 4; ++r) { mrun[r] = NEG_BIG; lrun[r] = 0.f; }

        #pragma unroll 1
        for (int kt = 0; kt < nk; ++kt) {
            const int bsel = kt & 1;
            if (kt + 1 < nk) issue_tile(kt + 1, bsel ^ 1);   // async prefetch

            const char* kb = smem + 8192 + bsel * 65536;
            const char* vb = kb + 32768;

            // ---- QK: 3-pass split-precision MFMA over this wave's 32 cols ----
            f32x4 sc[2];
            #pragma unroll
            for (int ct = 0; ct < 2; ++ct) {
                f32x4 a = f32x4{0.f, 0.f, 0.f, 0.f};
                #pragma unroll
                for (int ks = 0; ks < 2; ++ks) {
                    const int row = kh * 32 + ct * 16 + l15;
                    const int off = row * 128 +
                                    ((ks * 64 + l4 * 16) ^ ((row & 7) << 4));
                    short8b bh = *reinterpret_cast<const short8b*>(kb + off);
                    short8b bl = *reinterpret_cast<const short8b*>(kb + 16384 + off);
                    a = MFMA16(qf[1][ks], bh, a);   // qlo * khi
                    a = MFMA16(qf[0][ks], bl, a);   // qhi * klo
                    a = MFMA16(qf[0][ks], bh, a);   // qhi * khi
                }
                sc[ct] = a;
            }

            // causal mask: only the final k-tile
            if (kt == nk - 1) {
                #pragma unroll
                for (int ct = 0; ct < 2; ++ct) {
                    const int col = kt * 128 + kh * 32 + ct * 16 + l15;
                    #pragma unroll
                    for (int r = 0; r < 4; ++r) {
                        const int row = q0 + qh * 16 + l4 * 4 + r;
                        if (col > row) sc[ct][r] = NEG_BIG;
                    }
                }
            }

            // ---- wave-local online softmax (per kh group) ----
            float pm[4];
            #pragma unroll
            for (int r = 0; r < 4; ++r) pm[r] = fmaxf(sc[0][r], sc[1][r]);
            #pragma unroll
            for (int s = 1; s < 16; s <<= 1)
                #pragma unroll
                for (int r = 0; r < 4; ++r)
                    pm[r] = fmaxf(pm[r], __shfl_xor(pm[r], s));

            float alpha[4], ps[4];
            #pragma unroll
            for (int r = 0; r < 4; ++r) {
                const float mn = fmaxf(fmaxf(mrun[r], pm[r]), MCLAMP);
                alpha[r] = __expf(mrun[r] - mn);      // first tile: 0
                mrun[r] = mn;
                sc[0][r] = __expf(sc[0][r] - mn);     // masked -> 0 (mn>=-1e30)
                sc[1][r] = __expf(sc[1][r] - mn);
                ps[r] = sc[0][r] + sc[1][r];
            }
            #pragma unroll
            for (int s = 1; s < 16; s <<= 1)
                #pragma unroll
                for (int r = 0; r < 4; ++r) ps[r] += __shfl_xor(ps[r], s);
            #pragma unroll
            for (int r = 0; r < 4; ++r) lrun[r] = lrun[r] * alpha[r] + ps[r];
            #pragma unroll
            for (int c = 0; c < 4; ++c)
                #pragma unroll
                for (int r = 0; r < 4; ++r) of[c][r] *= alpha[r];

            // ---- P write (bf16, wave-private 16x32 block, swizzled) ----
            #pragma unroll
            for (int ct = 0; ct < 2; ++ct)
                #pragma unroll
                for (int r = 0; r < 4; ++r) {
                    const int row = qh * 16 + l4 * 4 + r;
                    const int col = kh * 32 + ct * 16 + l15;
                    const int off = row * 256 + ((col * 2) ^ ((row & 7) << 4));
                    *reinterpret_cast<unsigned short*>(smem + off) =
                        f2bf_rne(sc[ct][r]);
                }
            asm volatile("s_waitcnt lgkmcnt(0)" ::: "memory");
            __builtin_amdgcn_sched_barrier(0);

            // ---- P read (own block) + PV ----
            short8b pf;
            {
                const int row = qh * 16 + l15;
                const int off = row * 256 + ((kh * 64 + l4 * 16) ^ ((row & 7) << 4));
                pf = *reinterpret_cast<const short8b*>(smem + off);
            }
            #pragma unroll
            for (int ct = 0; ct < 4; ++ct) {
                const int vr = ct * 16 + l15;   // d-row of Vt
                const int voff = vr * 256 +
                                 ((kh * 64 + l4 * 16) ^ ((vr & 7) << 4));
                short8b vh = *reinterpret_cast<const short8b*>(vb + voff);
                short8b vl = *reinterpret_cast<const short8b*>(vb + 16384 + voff);
                of[ct] = MFMA16(pf, vl, of[ct]);
                of[ct] = MFMA16(pf, vh, of[ct]);
            }

            __syncthreads();   // end of tile: drains prefetch; orders LDS reuse
        }

        // ---- epilogue: merge the 4 independent kh groups ----
        if (l15 == 0) {
            #pragma unroll
            for (int r = 0; r < 4; ++r) {
                const int row = qh * 16 + l4 * 4 + r;
                Mg[kh][row] = mrun[r];
                Lg[kh][row] = lrun[r];
            }
        }
        __syncthreads();   // stats visible; buf region free for Opart

        float* Op = reinterpret_cast<float*>(smem + 8192);   // 32 KB alias
        #pragma unroll
        for (int r = 0; r < 4; ++r) {
            const int row = qh * 16 + l4 * 4 + r;
            const float M = fmaxf(fmaxf(Mg[0][row], Mg[1][row]),
                                  fmaxf(Mg[2][row], Mg[3][row]));
            const float L = Lg[0][row] * __expf(Mg[0][row] - M)
                          + Lg[1][row] * __expf(Mg[1][row] - M)
                          + Lg[2][row] * __expf(Mg[2][row] - M)
                          + Lg[3][row] * __expf(Mg[3][row] - M);
            const float al = __expf(mrun[r] - M);   // empty group -> 0
            #pragma unroll
            for (int c = 0; c < 4; ++c)
                Op[kh * 2048 + row * 64 + c * 16 + l15] = of[c][r] * al;
            if (kh == 0 && l15 == 0) Ltot[row] = L;
        }
        __syncthreads();

        // final reduce across groups + store
        {
            const int row = t >> 4;
            const int d0  = (t & 15) << 2;
            float4 s = {0.f, 0.f, 0.f, 0.f};
            #pragma unroll
            for (int g = 0; g < 4; ++g) {
                float4 v = *reinterpret_cast<const float4*>(
                    Op + g * 2048 + row * 64 + d0);
                s.x += v.x; s.y += v.y; s.z += v.z; s.w += v.w;
            }
            const float inv = 1.0f / Ltot[row];
            const size_t oi = (bS + q0 + row) * 64 + d0;
            if (f32o) {
                float4 o;
                o.x = s.x * inv; o.y = s.y * inv;
                o.z = s.z * inv; o.w = s.w * inv;
                *reinterpret_cast<float4*>((float*)out + oi) = o;
            } else {
                ushort4 o;
                o.x = f2bf_rne(s.x * inv);
                o.y = f2bf_rne(s.y * inv);
                o.z = f2bf_rne(s.z * inv);
                o.w = f2bf_rne(s.w * inv);
                *reinterpret_cast<ushort4*>((unsigned short*)out + oi) = o;
            }
        }
    }
}

extern "C" void kernel_launch(void* const* d_in, const int* in_sizes, int n_in,
                              void* d_out, int out_size, void* d_ws, size_t ws_size,
                              hipStream_t stream) {
    // workspace: 6 bf16 planes (Qh,Ql,Kh,Kl,Vth,Vtl) = 6 x 2MB = 12MB, + flag
    const size_t NP = (size_t)B_ * S_ * DH;
    unsigned short* Qhp  = (unsigned short*)d_ws;
    unsigned short* Qlp  = Qhp + NP;
    unsigned short* Khp  = Qhp + 2 * NP;
    unsigned short* Klp  = Qhp + 3 * NP;
    unsigned short* Vthp = Qhp + 4 * NP;
    unsigned short* Vtlp = Qhp + 5 * NP;
    int* flag = (int*)(Qhp + 6 * NP);

    detect_kernel<<<1, 256, 0, stream>>>((const unsigned short*)d_in[0], flag);

    proj_kernel<<<dim3(B_ * S_ / TM, 3), 256, 0, stream>>>(
        d_in[0], d_in[1], d_in[2],   // xq, xk, xv
        d_in[3], d_in[5], d_in[7],   // Wq, Wk, Wv
        d_in[4], d_in[6], d_in[8],   // bq, bk, bv
        Qhp, Qlp, Khp, Klp, Vthp, Vtlp, flag);

    flash_kernel<<<dim3(64, B_), 512, 0, stream>>>(
        Qhp, Qlp, Khp, Klp, Vthp, Vtlp, d_out, flag);
}

// Round 6
// 220.041 us; speedup vs baseline: 1.6995x; 1.1230x over previous
//
#include <hip/hip_runtime.h>
#include <hip/hip_bf16.h>

#define B_ 4
#define S_ 4096
#define DM 512
#define DH 64

#define NEG_BIG (-3.0e38f)
#define MCLAMP  (-1.0e30f)

typedef __attribute__((ext_vector_type(8))) short short8b;   // 8 bf16 (4 VGPRs)
typedef __attribute__((ext_vector_type(4))) float f32x4;     // MFMA C/D

__device__ __forceinline__ f32x4 MFMA16(short8b a, short8b b, f32x4 c) {
    return __builtin_amdgcn_mfma_f32_16x16x32_bf16(a, b, c, 0, 0, 0);
}

__device__ __forceinline__ float bf2f(unsigned short u) {
    unsigned int x = ((unsigned int)u) << 16;
    float f;
    __builtin_memcpy(&f, &x, 4);
    return f;
}
__device__ __forceinline__ unsigned short f2bf_rne(float f) {
    unsigned int u = __float_as_uint(f);
    u += 0x7FFFu + ((u >> 16) & 1u);
    return (unsigned short)(u >> 16);
}
__device__ __forceinline__ unsigned int pk2(unsigned short a, unsigned short b) {
    return (unsigned int)a | ((unsigned int)b << 16);
}

// async HBM->LDS DMA, 16B/lane (used by flash).
__device__ __forceinline__ void gload16(const void* gp, void* lp) {
    __builtin_amdgcn_global_load_lds(
        (const __attribute__((address_space(1))) void*)gp,
        (__attribute__((address_space(3))) void*)lp, 16, 0, 0);
}

// ---------------------------------------------------------------------------
// Dtype detector (unchanged): flag=1 -> inputs are fp32, 0 -> bf16.
// ---------------------------------------------------------------------------
__global__ void detect_kernel(const unsigned short* __restrict__ u,
                              int* __restrict__ flag) {
    __shared__ int cnt;
    if (threadIdx.x == 0) cnt = 0;
    __syncthreads();
    int w = 0;
    #pragma unroll
    for (int k = 0; k < 8; ++k) {
        unsigned short x = u[threadIdx.x * 8 + k];
        int e = (x >> 7) & 0xFF;
        if (e >= 135 || (e > 0 && e <= 95)) ++w;
    }
    atomicAdd(&cnt, w);
    __syncthreads();
    if (threadIdx.x == 0) *flag = (cnt > 64) ? 1 : 0;
}

// ---------------------------------------------------------------------------
// Projection v3: bf16 MFMA GEMM with hi/lo split precision (same scheme as
// flash). C[row, h] = sum_d X[row,d] * W[h,d] + b[h].
//  - Block: 256 thr (4 waves), tile 64 rows x 64 heads, BK=64 (8 chunks).
//    grid = (16384/64, 3) = 768 blocks = exactly 3/CU (balanced).
//  - Staging: per-thread fp32 (or bf16) loads -> hi/lo bf16 conversion ->
//    XOR-swizzled ds_write (byte ^= (row&7)<<4).  W (128 KB) is L2-resident.
//  - QK-proven fragment pattern: A=X rows, B=W rows, both row-major;
//    C col(lane&15) = head, row(4*(lane>>4)+reg) = X row.
//  - 3-pass MFMA: Xhi*Wlo + Xlo*Whi + Xhi*Whi  (fp32-grade).
//  - Epilogue: acc -> LDS f32 Cbuf[64][66] -> re-read row-wise (Q/K planes,
//    vectorized ushort8 stores) or column-wise (Vt transposed planes).
// LDS: 32 KB (Xh/Xl/Wh/Wl 8 KB each; Cbuf 16.9 KB aliases it).
// ---------------------------------------------------------------------------
#define PM 64
#define PK 64

__global__ __launch_bounds__(256) void proj_kernel(
    const void* __restrict__ xq, const void* __restrict__ xk,
    const void* __restrict__ xv,
    const void* __restrict__ Wq, const void* __restrict__ Wk,
    const void* __restrict__ Wv,
    const void* __restrict__ bq, const void* __restrict__ bk,
    const void* __restrict__ bv,
    unsigned short* __restrict__ Qhp, unsigned short* __restrict__ Qlp,
    unsigned short* __restrict__ Khp, unsigned short* __restrict__ Klp,
    unsigned short* __restrict__ Vthp, unsigned short* __restrict__ Vtlp,
    const int* __restrict__ flag)
{
    const int which = blockIdx.y;
    const void* x    = (which == 0) ? xq : (which == 1) ? xk : xv;
    const void* W    = (which == 0) ? Wq : (which == 1) ? Wk : Wv;
    const void* bias = (which == 0) ? bq : (which == 1) ? bk : bv;

    const bool f32 = (*flag != 0);
    const int row0 = blockIdx.x * PM;
    const int t    = threadIdx.x;
    const int lane = t & 63;
    const int w    = t >> 6;        // 0..3: wave owns rows w*16..+15
    const int l15  = lane & 15;
    const int l4   = lane >> 4;

    // [0,8192) Xh | [8192,16384) Xl | [16384,24576) Wh | [24576,32768) Wl
    // epilogue alias: float Cbuf[64][66] (16896 B)
    __shared__ __align__(16) char sm[32768];

    const int srow = t >> 2;        // 0..63 (X row / W head)
    const int sseg = t & 3;         // 16-elem segment within 64-k chunk
    const int swz  = (srow & 7) << 4;

    f32x4 acc[4];
    #pragma unroll
    for (int n = 0; n < 4; ++n) acc[n] = f32x4{0.f, 0.f, 0.f, 0.f};

    #pragma unroll 1
    for (int kc = 0; kc < DM / PK; ++kc) {
        const int k0 = kc * PK;
        __syncthreads();   // prev chunk's fragment reads complete

        if (f32) {
            #pragma unroll
            for (int m = 0; m < 2; ++m) {   // m=0: X, m=1: W
                const float* p = (m == 0)
                    ? (const float*)x + (size_t)(row0 + srow) * DM + k0 + sseg * 16
                    : (const float*)W + (size_t)srow * DM + k0 + sseg * 16;
                float v[16];
                #pragma unroll
                for (int j = 0; j < 4; ++j) {
                    float4 f = *reinterpret_cast<const float4*>(p + j * 4);
                    v[j * 4 + 0] = f.x; v[j * 4 + 1] = f.y;
                    v[j * 4 + 2] = f.z; v[j * 4 + 3] = f.w;
                }
                unsigned short hh[16], ll[16];
                #pragma unroll
                for (int j = 0; j < 16; ++j) {
                    unsigned short hb = f2bf_rne(v[j]);
                    hh[j] = hb;
                    ll[j] = f2bf_rne(v[j] - bf2f(hb));
                }
                char* dh = sm + m * 16384 + srow * 128;
                char* dl = dh + 8192;
                #pragma unroll
                for (int g = 0; g < 2; ++g) {
                    const int off = (sseg * 32 + g * 16) ^ swz;
                    uint4 hu, lu;
                    hu.x = pk2(hh[g*8+0], hh[g*8+1]); hu.y = pk2(hh[g*8+2], hh[g*8+3]);
                    hu.z = pk2(hh[g*8+4], hh[g*8+5]); hu.w = pk2(hh[g*8+6], hh[g*8+7]);
                    lu.x = pk2(ll[g*8+0], ll[g*8+1]); lu.y = pk2(ll[g*8+2], ll[g*8+3]);
                    lu.z = pk2(ll[g*8+4], ll[g*8+5]); lu.w = pk2(ll[g*8+6], ll[g*8+7]);
                    *reinterpret_cast<uint4*>(dh + off) = hu;
                    *reinterpret_cast<uint4*>(dl + off) = lu;
                }
            }
        } else {
            const uint4 z = {0u, 0u, 0u, 0u};
            #pragma unroll
            for (int m = 0; m < 2; ++m) {
                const unsigned short* p = (m == 0)
                    ? (const unsigned short*)x + (size_t)(row0 + srow) * DM + k0 + sseg * 16
                    : (const unsigned short*)W + (size_t)srow * DM + k0 + sseg * 16;
                char* dh = sm + m * 16384 + srow * 128;
                char* dl = dh + 8192;
                #pragma unroll
                for (int g = 0; g < 2; ++g) {
                    uint4 hv = *reinterpret_cast<const uint4*>(p + g * 8);
                    const int off = (sseg * 32 + g * 16) ^ swz;
                    *reinterpret_cast<uint4*>(dh + off) = hv;
                    *reinterpret_cast<uint4*>(dl + off) = z;   // lo = 0 (exact)
                }
            }
        }
        __syncthreads();   // stage visible

        // ---- fragments + 3-pass MFMA ----
        const int arow = w * 16 + l15;
        short8b xh[2], xl[2];
        #pragma unroll
        for (int ks = 0; ks < 2; ++ks) {
            const int off = arow * 128 + ((ks * 64 + l4 * 16) ^ ((arow & 7) << 4));
            xh[ks] = *reinterpret_cast<const short8b*>(sm + off);
            xl[ks] = *reinterpret_cast<const short8b*>(sm + 8192 + off);
        }
        #pragma unroll
        for (int n = 0; n < 4; ++n) {
            #pragma unroll
            for (int ks = 0; ks < 2; ++ks) {
                const int brow = n * 16 + l15;
                const int off = brow * 128 + ((ks * 64 + l4 * 16) ^ ((brow & 7) << 4));
                short8b wh = *reinterpret_cast<const short8b*>(sm + 16384 + off);
                short8b wl = *reinterpret_cast<const short8b*>(sm + 24576 + off);
                acc[n] = MFMA16(xh[ks], wl, acc[n]);   // xhi * wlo
                acc[n] = MFMA16(xl[ks], wh, acc[n]);   // xlo * whi
                acc[n] = MFMA16(xh[ks], wh, acc[n]);   // xhi * whi
            }
        }
    }

    // ---- epilogue: acc -> LDS f32 transpose buffer -> planes ----
    __syncthreads();   // last chunk's fragment reads complete
    float* C = reinterpret_cast<float*>(sm);   // [64][66]
    #pragma unroll
    for (int n = 0; n < 4; ++n)
        #pragma unroll
        for (int r = 0; r < 4; ++r)
            C[(w * 16 + l4 * 4 + r) * 66 + n * 16 + l15] = acc[n][r];
    __syncthreads();

    if (which < 2) {
        unsigned short* ph = (which == 0) ? Qhp : Khp;
        unsigned short* pl = (which == 0) ? Qlp : Klp;
        const float scale = (which == 0) ? 0.125f : 1.0f;   // 1/sqrt(64) in Q
        const int r_  = t >> 2;          // local row
        const int c0_ = (t & 3) * 16;    // head segment
        unsigned short hh[16], ll[16];
        #pragma unroll
        for (int j = 0; j < 16; ++j) {
            const float bv_ = f32 ? ((const float*)bias)[c0_ + j]
                                  : bf2f(((const unsigned short*)bias)[c0_ + j]);
            const float v = (C[r_ * 66 + c0_ + j] + bv_) * scale;
            unsigned short hb = f2bf_rne(v);
            hh[j] = hb;
            ll[j] = f2bf_rne(v - bf2f(hb));
        }
        const size_t off = (size_t)(row0 + r_) * DH + c0_;
        #pragma unroll
        for (int g = 0; g < 2; ++g) {
            uint4 hu, lu;
            hu.x = pk2(hh[g*8+0], hh[g*8+1]); hu.y = pk2(hh[g*8+2], hh[g*8+3]);
            hu.z = pk2(hh[g*8+4], hh[g*8+5]); hu.w = pk2(hh[g*8+6], hh[g*8+7]);
            lu.x = pk2(ll[g*8+0], ll[g*8+1]); lu.y = pk2(ll[g*8+2], ll[g*8+3]);
            lu.z = pk2(ll[g*8+4], ll[g*8+5]); lu.w = pk2(ll[g*8+6], ll[g*8+7]);
            *reinterpret_cast<uint4*>(ph + off + g * 8) = hu;
            *reinterpret_cast<uint4*>(pl + off + g * 8) = lu;
        }
    } else {
        const int c_ = t & 63;           // head (= Vt d-row)
        const int rb = (t >> 6) * 16;    // local row block
        const int bb = row0 >> 12;       // batch (S_=4096 rows per batch)
        const int s0 = row0 & (S_ - 1);
        const float bv_ = f32 ? ((const float*)bias)[c_]
                              : bf2f(((const unsigned short*)bias)[c_]);
        unsigned short hh[16], ll[16];
        #pragma unroll
        for (int i = 0; i < 16; ++i) {
            const float v = C[(rb + i) * 66 + c_] + bv_;
            unsigned short hb = f2bf_rne(v);
            hh[i] = hb;
            ll[i] = f2bf_rne(v - bf2f(hb));
        }
        const size_t off = (size_t)(bb * 64 + c_) * S_ + s0 + rb;
        #pragma unroll
        for (int g = 0; g < 2; ++g) {
            uint4 hu, lu;
            hu.x = pk2(hh[g*8+0], hh[g*8+1]); hu.y = pk2(hh[g*8+2], hh[g*8+3]);
            hu.z = pk2(hh[g*8+4], hh[g*8+5]); hu.w = pk2(hh[g*8+6], hh[g*8+7]);
            lu.x = pk2(ll[g*8+0], ll[g*8+1]); lu.y = pk2(ll[g*8+2], ll[g*8+3]);
            lu.z = pk2(ll[g*8+4], ll[g*8+5]); lu.w = pk2(ll[g*8+6], ll[g*8+7]);
            *reinterpret_cast<uint4*>(Vthp + off + g * 8) = hu;
            *reinterpret_cast<uint4*>(Vtlp + off + g * 8) = lu;
        }
    }
}

// ---------------------------------------------------------------------------
// Flash attention v5 (unchanged from round 5): global_load_lds DMA staging,
// double-buffered LDS, 8 waves, per-group online softmax + LSE merge.
// ---------------------------------------------------------------------------
__global__ __launch_bounds__(512, 2) void flash_kernel(
    const unsigned short* __restrict__ Qh, const unsigned short* __restrict__ Ql,
    const unsigned short* __restrict__ Kh, const unsigned short* __restrict__ Kl,
    const unsigned short* __restrict__ Vth, const unsigned short* __restrict__ Vtl,
    void* __restrict__ out, const int* __restrict__ flag)
{
    const int pair = blockIdx.x;   // 0..63
    const int b    = blockIdx.y;   // 0..3
    const int t    = threadIdx.x;
    const int lane = t & 63;
    const int w    = t >> 6;       // 0..7
    const int qh   = w & 1;        // q half (16 rows)
    const int kh   = w >> 1;       // key group (32 cols)
    const int l15  = lane & 15;
    const int l4   = lane >> 4;

    __shared__ __align__(16) char smem[8192 + 2 * 65536];
    __shared__ float Mg[4][32];
    __shared__ float Lg[4][32];
    __shared__ float Ltot[32];

    const size_t bS = (size_t)b * S_;
    const bool f32o = (*flag != 0);

    // Q staging map (per-thread stores, 1 uint4 each)
    const int qp   = t >> 8;            // plane
    const int qrow = (t & 255) >> 3;    // 0..31
    const int qsg  = t & 7;

    // K staging lane constants: chunk = 8 rows x 128B; source pre-swizzled.
    const int klaneoff = ((lane >> 3) << 7) +
                         ((((lane & 7) << 4)) ^ ((lane >> 3) << 4));
    // V staging lane constants: chunk = 4 rows x 256B; row parity par=cvp&1.
    const int vrl = lane >> 4;          // 0..3
    const int voff0 = (vrl << 13) + ((((lane & 15) << 4)) ^ (vrl << 4));
    const int voff1 = (vrl << 13) + ((((lane & 15) << 4)) ^ ((4 + vrl) << 4));

    const char* Khb = (const char*)Kh + bS * 128;          // 128 B per row
    const char* Klb = (const char*)Kl + bS * 128;
    const char* Vhb = (const char*)Vth + (size_t)b * 64 * 8192;  // 8192 B per d-row
    const char* Vlb = (const char*)Vtl + (size_t)b * 64 * 8192;

    auto issue_tile = [&](int kt, int bsel) {
        char* buf = smem + 8192 + bsel * 65536;
        if (w < 4) {
            #pragma unroll
            for (int j = 0; j < 8; ++j) {
                const int c2  = w * 8 + j;          // 0..31
                const int p   = c2 >> 4;
                const int ckp = c2 & 15;
                const char* g = (p ? Klb : Khb) +
                                (size_t)kt * 16384 + ckp * 1024 + klaneoff;
                gload16(g, buf + p * 16384 + ckp * 1024);
            }
        } else {
            #pragma unroll
            for (int j = 0; j < 8; ++j) {
                const int c2  = (w - 4) * 8 + j;    // 0..31
                const int p   = c2 >> 4;
                const int cvp = c2 & 15;
                const int vo  = (cvp & 1) ? voff1 : voff0;
                const char* g = (p ? Vlb : Vhb) +
                                (size_t)cvp * 32768 + (size_t)kt * 256 + vo;
                gload16(g, buf + 32768 + p * 16384 + cvp * 1024);
            }
        }
    };

    #pragma unroll 1
    for (int hf = 0; hf < 2; ++hf) {
        const int qt = hf ? (127 - pair) : pair;
        const int q0 = qt << 5;
        const int nk = (qt >> 2) + 1;   // 128-key tiles; pair sum is 33

        __syncthreads();   // prior half fully done

        {
            const unsigned short* src = qp ? Ql : Qh;
            uint4 v = *reinterpret_cast<const uint4*>(
                src + (bS + q0 + qrow) * 64 + qsg * 8);
            const int off = qp * 4096 + qrow * 128 +
                            ((qsg * 16) ^ ((qrow & 7) << 4));
            *reinterpret_cast<uint4*>(smem + off) = v;
        }
        issue_tile(0, 0);
        __syncthreads();   // Q stores + tile0 DMA complete

        short8b qf[2][2];   // [plane][ks]
        #pragma unroll
        for (int p = 0; p < 2; ++p)
            #pragma unroll
            for (int ks = 0; ks < 2; ++ks) {
                const int row = qh * 16 + l15;
                const int off = p * 4096 + row * 128 +
                                ((ks * 64 + l4 * 16) ^ ((row & 7) << 4));
                qf[p][ks] = *reinterpret_cast<const short8b*>(smem + off);
            }
        __syncthreads();   // Q reads done before P aliases the region

        f32x4 of[4];
        of[0] = f32x4{0.f, 0.f, 0.f, 0.f};
        of[1] = f32x4{0.f, 0.f, 0.f, 0.f};
        of[2] = f32x4{0.f, 0.f, 0.f, 0.f};
        of[3] = f32x4{0.f, 0.f, 0.f, 0.f};
        float mrun[4], lrun[4];
        #pragma unroll
        for (int r = 0; r < 4; ++r) { mrun[r] = NEG_BIG; lrun[r] = 0.f; }

        #pragma unroll 1
        for (int kt = 0; kt < nk; ++kt) {
            const int bsel = kt & 1;
            if (kt + 1 < nk) issue_tile(kt + 1, bsel ^ 1);   // async prefetch

            const char* kb = smem + 8192 + bsel * 65536;
            const char* vb = kb + 32768;

            f32x4 sc[2];
            #pragma unroll
            for (int ct = 0; ct < 2; ++ct) {
                f32x4 a = f32x4{0.f, 0.f, 0.f, 0.f};
                #pragma unroll
                for (int ks = 0; ks < 2; ++ks) {
                    const int row = kh * 32 + ct * 16 + l15;
                    const int off = row * 128 +
                                    ((ks * 64 + l4 * 16) ^ ((row & 7) << 4));
                    short8b bh = *reinterpret_cast<const short8b*>(kb + off);
                    short8b bl = *reinterpret_cast<const short8b*>(kb + 16384 + off);
                    a = MFMA16(qf[1][ks], bh, a);   // qlo * khi
                    a = MFMA16(qf[0][ks], bl, a);   // qhi * klo
                    a = MFMA16(qf[0][ks], bh, a);   // qhi * khi
                }
                sc[ct] = a;
            }

            if (kt == nk - 1) {
                #pragma unroll
                for (int ct = 0; ct < 2; ++ct) {
                    const int col = kt * 128 + kh * 32 + ct * 16 + l15;
                    #pragma unroll
                    for (int r = 0; r < 4; ++r) {
                        const int row = q0 + qh * 16 + l4 * 4 + r;
                        if (col > row) sc[ct][r] = NEG_BIG;
                    }
                }
            }

            float pm[4];
            #pragma unroll
            for (int r = 0; r < 4; ++r) pm[r] = fmaxf(sc[0][r], sc[1][r]);
            #pragma unroll
            for (int s = 1; s < 16; s <<= 1)
                #pragma unroll
                for (int r = 0; r < 4; ++r)
                    pm[r] = fmaxf(pm[r], __shfl_xor(pm[r], s));

            float alpha[4], ps[4];
            #pragma unroll
            for (int r = 0; r < 4; ++r) {
                const float mn = fmaxf(fmaxf(mrun[r], pm[r]), MCLAMP);
                alpha[r] = __expf(mrun[r] - mn);      // first tile: 0
                mrun[r] = mn;
                sc[0][r] = __expf(sc[0][r] - mn);     // masked -> 0
                sc[1][r] = __expf(sc[1][r] - mn);
                ps[r] = sc[0][r] + sc[1][r];
            }
            #pragma unroll
            for (int s = 1; s < 16; s <<= 1)
                #pragma unroll
                for (int r = 0; r < 4; ++r) ps[r] += __shfl_xor(ps[r], s);
            #pragma unroll
            for (int r = 0; r < 4; ++r) lrun[r] = lrun[r] * alpha[r] + ps[r];
            #pragma unroll
            for (int c = 0; c < 4; ++c)
                #pragma unroll
                for (int r = 0; r < 4; ++r) of[c][r] *= alpha[r];

            #pragma unroll
            for (int ct = 0; ct < 2; ++ct)
                #pragma unroll
                for (int r = 0; r < 4; ++r) {
                    const int row = qh * 16 + l4 * 4 + r;
                    const int col = kh * 32 + ct * 16 + l15;
                    const int off = row * 256 + ((col * 2) ^ ((row & 7) << 4));
                    *reinterpret_cast<unsigned short*>(smem + off) =
                        f2bf_rne(sc[ct][r]);
                }
            asm volatile("s_waitcnt lgkmcnt(0)" ::: "memory");
            __builtin_amdgcn_sched_barrier(0);

            short8b pf;
            {
                const int row = qh * 16 + l15;
                const int off = row * 256 + ((kh * 64 + l4 * 16) ^ ((row & 7) << 4));
                pf = *reinterpret_cast<const short8b*>(smem + off);
            }
            #pragma unroll
            for (int ct = 0; ct < 4; ++ct) {
                const int vr = ct * 16 + l15;   // d-row of Vt
                const int voff = vr * 256 +
                                 ((kh * 64 + l4 * 16) ^ ((vr & 7) << 4));
                short8b vh = *reinterpret_cast<const short8b*>(vb + voff);
                short8b vl = *reinterpret_cast<const short8b*>(vb + 16384 + voff);
                of[ct] = MFMA16(pf, vl, of[ct]);
                of[ct] = MFMA16(pf, vh, of[ct]);
            }

            __syncthreads();   // end of tile: drains prefetch; orders LDS reuse
        }

        if (l15 == 0) {
            #pragma unroll
            for (int r = 0; r < 4; ++r) {
                const int row = qh * 16 + l4 * 4 + r;
                Mg[kh][row] = mrun[r];
                Lg[kh][row] = lrun[r];
            }
        }
        __syncthreads();

        float* Op = reinterpret_cast<float*>(smem + 8192);   // 32 KB alias
        #pragma unroll
        for (int r = 0; r < 4; ++r) {
            const int row = qh * 16 + l4 * 4 + r;
            const float M = fmaxf(fmaxf(Mg[0][row], Mg[1][row]),
                                  fmaxf(Mg[2][row], Mg[3][row]));
            const float L = Lg[0][row] * __expf(Mg[0][row] - M)
                          + Lg[1][row] * __expf(Mg[1][row] - M)
                          + Lg[2][row] * __expf(Mg[2][row] - M)
                          + Lg[3][row] * __expf(Mg[3][row] - M);
            const float al = __expf(mrun[r] - M);   // empty group -> 0
            #pragma unroll
            for (int c = 0; c < 4; ++c)
                Op[kh * 2048 + row * 64 + c * 16 + l15] = of[c][r] * al;
            if (kh == 0 && l15 == 0) Ltot[row] = L;
        }
        __syncthreads();

        {
            const int row = t >> 4;
            const int d0  = (t & 15) << 2;
            float4 s = {0.f, 0.f, 0.f, 0.f};
            #pragma unroll
            for (int g = 0; g < 4; ++g) {
                float4 v = *reinterpret_cast<const float4*>(
                    Op + g * 2048 + row * 64 + d0);
                s.x += v.x; s.y += v.y; s.z += v.z; s.w += v.w;
            }
            const float inv = 1.0f / Ltot[row];
            const size_t oi = (bS + q0 + row) * 64 + d0;
            if (f32o) {
                float4 o;
                o.x = s.x * inv; o.y = s.y * inv;
                o.z = s.z * inv; o.w = s.w * inv;
                *reinterpret_cast<float4*>((float*)out + oi) = o;
            } else {
                ushort4 o;
                o.x = f2bf_rne(s.x * inv);
                o.y = f2bf_rne(s.y * inv);
                o.z = f2bf_rne(s.z * inv);
                o.w = f2bf_rne(s.w * inv);
                *reinterpret_cast<ushort4*>((unsigned short*)out + oi) = o;
            }
        }
    }
}

extern "C" void kernel_launch(void* const* d_in, const int* in_sizes, int n_in,
                              void* d_out, int out_size, void* d_ws, size_t ws_size,
                              hipStream_t stream) {
    // workspace: 6 bf16 planes (Qh,Ql,Kh,Kl,Vth,Vtl) = 6 x 2MB = 12MB, + flag
    const size_t NP = (size_t)B_ * S_ * DH;
    unsigned short* Qhp  = (unsigned short*)d_ws;
    unsigned short* Qlp  = Qhp + NP;
    unsigned short* Khp  = Qhp + 2 * NP;
    unsigned short* Klp  = Qhp + 3 * NP;
    unsigned short* Vthp = Qhp + 4 * NP;
    unsigned short* Vtlp = Qhp + 5 * NP;
    int* flag = (int*)(Qhp + 6 * NP);

    detect_kernel<<<1, 256, 0, stream>>>((const unsigned short*)d_in[0], flag);

    proj_kernel<<<dim3(B_ * S_ / PM, 3), 256, 0, stream>>>(
        d_in[0], d_in[1], d_in[2],   // xq, xk, xv
        d_in[3], d_in[5], d_in[7],   // Wq, Wk, Wv
        d_in[4], d_in[6], d_in[8],   // bq, bk, bv
        Qhp, Qlp, Khp, Klp, Vthp, Vtlp, flag);

    flash_kernel<<<dim3(64, B_), 512, 0, stream>>>(
        Qhp, Qlp, Khp, Klp, Vthp, Vtlp, d_out, flag);
}